// Round 6
// baseline (267.325 us; speedup 1.0000x reference)
//
#include <hip/hip_runtime.h>

// CrossAttention with LoRA (folded). B=16, C=64, hw=4096, L=77, COND=768, HEADS=8, dh=8.
// Round 6: R3 geometry (512 thr, wave=head, lane=px, grid 64x16), but k/v and
// weight reads go through the VECTOR memory pipe (global_load, in-order vmcnt,
// compiler-pipelined) instead of scalar s_load (out-of-order, lgkmcnt(0) drains).
// The `zero` kernel arg (runtime 0) * lane id defeats scalar-promotion of the
// wave-uniform addresses. Math order identical to R3 (absmax must stay 2.441e-4).
// Pipeline: prep_weights -> kvproj (split-K) -> kvreduce -> megattn.

#define HW   4096
#define CHN  64
#define LSEQ 77
#define CD   768
#define NB   16
#define PAD  66

// workspace float offsets
#define OFF_WQ 0
#define OFF_WK 4096
#define OFF_WV 53248
#define OFF_WO 102400
#define OFF_K  106496
#define OFF_V  185344
#define OFF_PA 264192   // partials [2][12][16][77*64]

#define QF 0.51011784563163f  // SCALE * log2(e) = 8^-0.5 * 1.442695...

__global__ __launch_bounds__(256) void prep_weights(
    const float* __restrict__ Wq, const float* __restrict__ Aq, const float* __restrict__ Bq,
    const float* __restrict__ Wk, const float* __restrict__ Ak, const float* __restrict__ Bk,
    const float* __restrict__ Wv, const float* __restrict__ Av, const float* __restrict__ Bv,
    const float* __restrict__ Wo, const float* __restrict__ Ao, const float* __restrict__ Bo,
    float* __restrict__ ws) {
  int idx = blockIdx.x * 256 + threadIdx.x;   // 416*256 = 106496 exact
  const float *W, *A, *Bm;
  float* out;
  int in_d, local;
  float scale = 1.0f;
  if (idx < 4096)        { W = Wq; A = Aq; Bm = Bq; out = ws + OFF_WQ; in_d = 64;  local = idx; scale = QF; }
  else if (idx < 53248)  { W = Wk; A = Ak; Bm = Bk; out = ws + OFF_WK; in_d = 768; local = idx - 4096; }
  else if (idx < 102400) { W = Wv; A = Av; Bm = Bv; out = ws + OFF_WV; in_d = 768; local = idx - 53248; }
  else                   { W = Wo; A = Ao; Bm = Bo; out = ws + OFF_WO; in_d = 64;  local = idx - 102400; }
  int co = local & 63;
  int c  = local >> 6;
  float val = W[co * in_d + c];
  #pragma unroll
  for (int r = 0; r < 8; r++) val += Bm[co * 8 + r] * A[r * in_d + c];
  out[local] = val * scale;   // local == c*64+co : W_eff^T [in][out]
}

// split-K partial projection of cond -> k/v. grid (12 kchunks, 2 kv, 16 b), block 128 (lane = l).
__global__ __launch_bounds__(128, 2) void kvproj(
    const float* __restrict__ cond,  // [16][77][768]
    const float* __restrict__ wkT,   // [768][64]
    const float* __restrict__ wvT,
    float* __restrict__ part) {      // [2][12][16][77*64]
  int chunk = blockIdx.x;
  int kv    = blockIdx.y;
  int b     = blockIdx.z;
  int l     = threadIdx.x;
  if (l >= LSEQ) return;
  const float* wT = kv ? wvT : wkT;
  int c0 = chunk * 64;
  const float* xr = cond + (b * LSEQ + l) * CD + c0;
  float zr[64];
  #pragma unroll
  for (int i = 0; i < 16; i++) {
    float4 t4 = ((const float4*)xr)[i];
    zr[4*i] = t4.x; zr[4*i+1] = t4.y; zr[4*i+2] = t4.z; zr[4*i+3] = t4.w;
  }
  float acc[64];
  #pragma unroll
  for (int co = 0; co < 64; co++) acc[co] = 0.f;
  #pragma unroll 4
  for (int c = 0; c < 64; c++) {
    float zv = zr[c];
    #pragma unroll
    for (int co = 0; co < 64; co++) acc[co] = fmaf(zv, wT[(c0 + c) * 64 + co], acc[co]);
  }
  float* pout = part + (((kv * 12 + chunk) * NB + b) * LSEQ + l) * 64;
  #pragma unroll
  for (int i = 0; i < 16; i++) {
    ((float4*)pout)[i] = make_float4(acc[4*i], acc[4*i+1], acc[4*i+2], acc[4*i+3]);
  }
}

__global__ __launch_bounds__(256) void kvreduce(
    const float* __restrict__ part,
    const float* __restrict__ bk, const float* __restrict__ bv,
    float* __restrict__ kbuf, float* __restrict__ vbuf) {
  int idx = blockIdx.x * 256 + threadIdx.x;  // 616*256 = 157696 exact
  int kv = idx / (NB * LSEQ * 64);
  int r  = idx - kv * (NB * LSEQ * 64);
  int co = idx & 63;
  float val = kv ? bv[co] : bk[co];
  #pragma unroll
  for (int ch = 0; ch < 12; ch++)
    val += part[(kv * 12 + ch) * (NB * LSEQ * 64) + r];
  (kv ? vbuf : kbuf)[r] = val;
}

// Fused q-proj + attention + o-proj, one wave per head.
// grid (64 ptiles of 64 px, 16 b), block 512 (8 waves). lane = px, wave = head.
// k/v + weights via vector global loads (vz trick) -> vmcnt-pipelined broadcasts.
__global__ __launch_bounds__(512, 4) void megattn(
    const float* __restrict__ z,     // [16][64][4096]
    const float* __restrict__ wqT,   // [64][64] [c][co], pre-scaled by QF
    const float* __restrict__ bq,
    const float* __restrict__ kbuf,  // [16][77][64]
    const float* __restrict__ vbuf,
    const float* __restrict__ woT,   // [64][64] [c][co]
    const float* __restrict__ bo,
    float* __restrict__ out,         // [16][64][4096]
    int zero) {                      // runtime 0: defeats scalar-promotion
  __shared__ float ao[64 * PAD];     // 16896 B
  int b  = blockIdx.y;
  int p0 = blockIdx.x * 64;
  int t  = threadIdx.x;
  int h  = __builtin_amdgcn_readfirstlane(t >> 6);  // wave index == head (uniform)
  int px = t & 63;
  int vz = zero * px;                // == 0, but lane-dependent -> vector loads

  // ---- Q phase: q[px][8h..8h+7]; weights via vector pipe ----
  float q[8];
  #pragma unroll
  for (int d = 0; d < 8; d++) q[d] = bq[8 * h + d] * QF;
  {
    const float* zb = z + b * (CHN * HW) + p0 + px;
    const float* wq = wqT + 8 * h + vz;
    #pragma unroll 8
    for (int c = 0; c < 64; c++) {
      float zv = zb[c * HW];
      #pragma unroll
      for (int d = 0; d < 8; d++) q[d] = fmaf(zv, wq[c * 64 + d], q[d]);
    }
  }

  // ---- Attention: k/v via vector pipe (in-order vmcnt, compiler-pipelined) ----
  float acc[8];
  float li = 0.f;
  #pragma unroll
  for (int d = 0; d < 8; d++) acc[d] = 0.f;
  {
    const float* kb = kbuf + b * (LSEQ * 64) + 8 * h + vz;
    const float* vb = vbuf + b * (LSEQ * 64) + 8 * h + vz;
    #pragma unroll 7
    for (int j = 0; j < LSEQ; j++) {
      float kf[8], vf[8];
      #pragma unroll
      for (int d = 0; d < 8; d++) kf[d] = kb[j * 64 + d];
      #pragma unroll
      for (int d = 0; d < 8; d++) vf[d] = vb[j * 64 + d];
      float s = q[0] * kf[0];
      #pragma unroll
      for (int d = 1; d < 8; d++) s = fmaf(q[d], kf[d], s);
      float e = __builtin_amdgcn_exp2f(s);
      li += e;
      #pragma unroll
      for (int d = 0; d < 8; d++) acc[d] = fmaf(e, vf[d], acc[d]);
    }
  }

  // ---- ao gather: [px][PAD=66] float2 stores (2-way alias = free; 0 conflicts measured) ----
  {
    float inv = 1.0f / li;
    #pragma unroll
    for (int d = 0; d < 8; d += 2)
      *(float2*)(ao + px * PAD + 8 * h + d) = make_float2(acc[d] * inv, acc[d + 1] * inv);
  }
  __syncthreads();

  // ---- O phase: out[8h+i][px] = ao[px][:] . woT[:][8h+i] + bo; weights vector pipe ----
  {
    float o[8];
    #pragma unroll
    for (int i = 0; i < 8; i++) o[i] = bo[8 * h + i];
    const float* wo = woT + 8 * h + vz;
    const float* aor = ao + px * PAD;
    #pragma unroll 8
    for (int c = 0; c < 64; c += 2) {
      float2 a2 = *(const float2*)(aor + c);
      #pragma unroll
      for (int i = 0; i < 8; i++) o[i] = fmaf(a2.x, wo[c * 64 + i], o[i]);
      #pragma unroll
      for (int i = 0; i < 8; i++) o[i] = fmaf(a2.y, wo[(c + 1) * 64 + i], o[i]);
    }
    float* ob = out + b * (CHN * HW) + p0 + px;
    #pragma unroll
    for (int i = 0; i < 8; i++) ob[(8 * h + i) * HW] = o[i];
  }
}

extern "C" void kernel_launch(void* const* d_in, const int* in_sizes, int n_in,
                              void* d_out, int out_size, void* d_ws, size_t ws_size,
                              hipStream_t stream) {
  const float* z    = (const float*)d_in[0];
  const float* cond = (const float*)d_in[1];
  const float* Wq = (const float*)d_in[2];  const float* bq = (const float*)d_in[3];
  const float* Aq = (const float*)d_in[4];  const float* Bq = (const float*)d_in[5];
  const float* Wk = (const float*)d_in[6];  const float* bk = (const float*)d_in[7];
  const float* Ak = (const float*)d_in[8];  const float* Bk = (const float*)d_in[9];
  const float* Wv = (const float*)d_in[10]; const float* bv = (const float*)d_in[11];
  const float* Av = (const float*)d_in[12]; const float* Bv = (const float*)d_in[13];
  const float* Wo = (const float*)d_in[14]; const float* bo = (const float*)d_in[15];
  const float* Ao = (const float*)d_in[16]; const float* Bo = (const float*)d_in[17];
  float* ws  = (float*)d_ws;
  float* out = (float*)d_out;

  prep_weights<<<416, 256, 0, stream>>>(Wq, Aq, Bq, Wk, Ak, Bk, Wv, Av, Bv, Wo, Ao, Bo, ws);
  kvproj<<<dim3(12, 2, 16), 128, 0, stream>>>(cond, ws + OFF_WK, ws + OFF_WV, ws + OFF_PA);
  kvreduce<<<616, 256, 0, stream>>>(ws + OFF_PA, bk, bv, ws + OFF_K, ws + OFF_V);
  megattn<<<dim3(64, 16), 512, 0, stream>>>(z, ws + OFF_WQ, bq, ws + OFF_K, ws + OFF_V,
                                            ws + OFF_WO, bo, out, 0);
}

// Round 7
// 183.726 us; speedup vs baseline: 1.4550x; 1.4550x over previous
//
#include <hip/hip_runtime.h>

// CrossAttention with LoRA (folded). B=16, C=64, hw=4096, L=77, COND=768, HEADS=8, dh=8.
// Round 7: megattn with LDS k/v + 8 px/thread ILP.
//   block 256 (4 waves), half-wave = head (h = t>>5), lane l = t&31,
//   px = p0 + l + 32*i (i<8)  -> all LDS access strides are 66 or 528 floats
//   ... 66 ≡ 2 (mod 32) per-lane -> <=2-way bank alias (free, m136).
//   k/v staged in LDS once (9856 floats); attention reads 4 ds_read_b128 per
//   j per wave, amortized over 8 px; 8 independent dot/exp/acc chains per j.
//   grid (16 ptiles, 16 b) = 256 blocks = 1/CU; ILP carries latency hiding.
// Pipeline: prep_weights -> kvproj (split-K) -> kvreduce -> megattn.

#define HW   4096
#define CHN  64
#define LSEQ 77
#define CD   768
#define NB   16
#define PAD  66

// workspace float offsets
#define OFF_WQ 0
#define OFF_WK 4096
#define OFF_WV 53248
#define OFF_WO 102400
#define OFF_K  106496
#define OFF_V  185344
#define OFF_PA 264192   // partials [2][12][16][77*64]

#define QF 0.51011784563163f  // SCALE * log2(e) = 8^-0.5 * 1.442695...

__global__ __launch_bounds__(256) void prep_weights(
    const float* __restrict__ Wq, const float* __restrict__ Aq, const float* __restrict__ Bq,
    const float* __restrict__ Wk, const float* __restrict__ Ak, const float* __restrict__ Bk,
    const float* __restrict__ Wv, const float* __restrict__ Av, const float* __restrict__ Bv,
    const float* __restrict__ Wo, const float* __restrict__ Ao, const float* __restrict__ Bo,
    float* __restrict__ ws) {
  int idx = blockIdx.x * 256 + threadIdx.x;   // 416*256 = 106496 exact
  const float *W, *A, *Bm;
  float* out;
  int in_d, local;
  float scale = 1.0f;
  if (idx < 4096)        { W = Wq; A = Aq; Bm = Bq; out = ws + OFF_WQ; in_d = 64;  local = idx; scale = QF; }
  else if (idx < 53248)  { W = Wk; A = Ak; Bm = Bk; out = ws + OFF_WK; in_d = 768; local = idx - 4096; }
  else if (idx < 102400) { W = Wv; A = Av; Bm = Bv; out = ws + OFF_WV; in_d = 768; local = idx - 53248; }
  else                   { W = Wo; A = Ao; Bm = Bo; out = ws + OFF_WO; in_d = 64;  local = idx - 102400; }
  int co = local & 63;
  int c  = local >> 6;
  float val = W[co * in_d + c];
  #pragma unroll
  for (int r = 0; r < 8; r++) val += Bm[co * 8 + r] * A[r * in_d + c];
  out[local] = val * scale;   // local == c*64+co : W_eff^T [in][out]
}

// split-K partial projection of cond -> k/v. grid (12 kchunks, 2 kv, 16 b), block 128 (lane = l).
__global__ __launch_bounds__(128, 2) void kvproj(
    const float* __restrict__ cond,  // [16][77][768]
    const float* __restrict__ wkT,   // [768][64]
    const float* __restrict__ wvT,
    float* __restrict__ part) {      // [2][12][16][77*64]
  int chunk = blockIdx.x;
  int kv    = blockIdx.y;
  int b     = blockIdx.z;
  int l     = threadIdx.x;
  if (l >= LSEQ) return;
  const float* wT = kv ? wvT : wkT;
  int c0 = chunk * 64;
  const float* xr = cond + (b * LSEQ + l) * CD + c0;
  float zr[64];
  #pragma unroll
  for (int i = 0; i < 16; i++) {
    float4 t4 = ((const float4*)xr)[i];
    zr[4*i] = t4.x; zr[4*i+1] = t4.y; zr[4*i+2] = t4.z; zr[4*i+3] = t4.w;
  }
  float acc[64];
  #pragma unroll
  for (int co = 0; co < 64; co++) acc[co] = 0.f;
  #pragma unroll 4
  for (int c = 0; c < 64; c++) {
    float zv = zr[c];
    #pragma unroll
    for (int co = 0; co < 64; co++) acc[co] = fmaf(zv, wT[(c0 + c) * 64 + co], acc[co]);
  }
  float* pout = part + (((kv * 12 + chunk) * NB + b) * LSEQ + l) * 64;
  #pragma unroll
  for (int i = 0; i < 16; i++) {
    ((float4*)pout)[i] = make_float4(acc[4*i], acc[4*i+1], acc[4*i+2], acc[4*i+3]);
  }
}

__global__ __launch_bounds__(256) void kvreduce(
    const float* __restrict__ part,
    const float* __restrict__ bk, const float* __restrict__ bv,
    float* __restrict__ kbuf, float* __restrict__ vbuf) {
  int idx = blockIdx.x * 256 + threadIdx.x;  // 616*256 = 157696 exact
  int kv = idx / (NB * LSEQ * 64);
  int r  = idx - kv * (NB * LSEQ * 64);
  int co = idx & 63;
  float val = kv ? bv[co] : bk[co];
  #pragma unroll
  for (int ch = 0; ch < 12; ch++)
    val += part[(kv * 12 + ch) * (NB * LSEQ * 64) + r];
  (kv ? vbuf : kbuf)[r] = val;
}

// Fused q-proj + attention + o-proj. Block 256 = 4 waves; half-wave = head.
// Each thread: 8 px (= l + 32*i) for one head. grid (16 ptiles of 256 px, 16 b).
__global__ __launch_bounds__(256) void megattn(
    const float* __restrict__ z,     // [16][64][4096]
    const float* __restrict__ wqT,   // [64][64] [c][co], pre-scaled by QF
    const float* __restrict__ bq,
    const float* __restrict__ kbuf,  // [16][77][64]
    const float* __restrict__ vbuf,
    const float* __restrict__ woT,   // [64][64] [c][co]
    const float* __restrict__ bo,
    float* __restrict__ out) {       // [16][64][4096]
  __shared__ float smem[256 * PAD];  // 67584 B; phase 1: k|v (9856 fl), phase 2: ao[256][66]
  int b  = blockIdx.y;
  int p0 = blockIdx.x * 256;
  int t  = threadIdx.x;
  int h  = t >> 5;    // half-wave head
  int l  = t & 31;

  // ---- stage k,v into LDS (once per block) ----
  float* ks = smem;              // [77][64]
  float* vs = smem + LSEQ * 64;  // [77][64]
  {
    const float4* ksrc = (const float4*)(kbuf + b * LSEQ * 64);
    const float4* vsrc = (const float4*)(vbuf + b * LSEQ * 64);
    float4* kd = (float4*)ks;
    float4* vd = (float4*)vs;
    for (int i = t; i < LSEQ * 16; i += 256) { kd[i] = ksrc[i]; vd[i] = vsrc[i]; }
  }

  // ---- Q phase (global only; runs while staging drains) ----
  float q[8][8];   // [px_i][d]
  #pragma unroll
  for (int i = 0; i < 8; i++)
    #pragma unroll
    for (int d = 0; d < 8; d++) q[i][d] = bq[8 * h + d] * QF;
  {
    const float* zb = z + b * (CHN * HW) + p0 + l;
    const float* wq = wqT + 8 * h;
    #pragma unroll 2
    for (int c = 0; c < 64; c++) {
      float zv[8];
      #pragma unroll
      for (int i = 0; i < 8; i++) zv[i] = zb[c * HW + 32 * i];
      float4 w0 = *(const float4*)(wq + c * 64);
      float4 w1 = *(const float4*)(wq + c * 64 + 4);
      #pragma unroll
      for (int i = 0; i < 8; i++) {
        q[i][0] = fmaf(zv[i], w0.x, q[i][0]);
        q[i][1] = fmaf(zv[i], w0.y, q[i][1]);
        q[i][2] = fmaf(zv[i], w0.z, q[i][2]);
        q[i][3] = fmaf(zv[i], w0.w, q[i][3]);
        q[i][4] = fmaf(zv[i], w1.x, q[i][4]);
        q[i][5] = fmaf(zv[i], w1.y, q[i][5]);
        q[i][6] = fmaf(zv[i], w1.z, q[i][6]);
        q[i][7] = fmaf(zv[i], w1.w, q[i][7]);
      }
    }
  }
  __syncthreads();   // staging visible

  // ---- Attention: 4 ds_read_b128 per j per wave, 8 indep px chains ----
  float acc[8][8];
  float li[8];
  #pragma unroll
  for (int i = 0; i < 8; i++) {
    li[i] = 0.f;
    #pragma unroll
    for (int d = 0; d < 8; d++) acc[i][d] = 0.f;
  }
  #pragma unroll 2
  for (int j = 0; j < LSEQ; j++) {
    float4 k0 = *(const float4*)(ks + j * 64 + 8 * h);
    float4 k1 = *(const float4*)(ks + j * 64 + 8 * h + 4);
    float4 v0 = *(const float4*)(vs + j * 64 + 8 * h);
    float4 v1 = *(const float4*)(vs + j * 64 + 8 * h + 4);
    #pragma unroll
    for (int i = 0; i < 8; i++) {
      float sa = fmaf(q[i][3], k0.w, fmaf(q[i][2], k0.z, fmaf(q[i][1], k0.y, q[i][0] * k0.x)));
      float sb = fmaf(q[i][7], k1.w, fmaf(q[i][6], k1.z, fmaf(q[i][5], k1.y, q[i][4] * k1.x)));
      float e = __builtin_amdgcn_exp2f(sa + sb);
      li[i] += e;
      acc[i][0] = fmaf(e, v0.x, acc[i][0]);
      acc[i][1] = fmaf(e, v0.y, acc[i][1]);
      acc[i][2] = fmaf(e, v0.z, acc[i][2]);
      acc[i][3] = fmaf(e, v0.w, acc[i][3]);
      acc[i][4] = fmaf(e, v1.x, acc[i][4]);
      acc[i][5] = fmaf(e, v1.y, acc[i][5]);
      acc[i][6] = fmaf(e, v1.z, acc[i][6]);
      acc[i][7] = fmaf(e, v1.w, acc[i][7]);
    }
  }
  __syncthreads();   // all k/v reads done; smem reusable as ao

  // ---- ao gather: ao[px_local][PAD] ; lane stride 66 ≡ 2 mod 32 -> 2-way, free ----
  float* ao = smem;
  #pragma unroll
  for (int i = 0; i < 8; i++) {
    float inv = 1.0f / li[i];
    float* aor = ao + (l + 32 * i) * PAD + 8 * h;
    #pragma unroll
    for (int d = 0; d < 8; d += 2)
      *(float2*)(aor + d) = make_float2(acc[i][d] * inv, acc[i][d + 1] * inv);
  }
  __syncthreads();

  // ---- O phase: out[8h+d][px] = ao[px][:] . woT[:][8h+d] + bo ----
  {
    float o[8][8];   // [px_i][out_d]
    #pragma unroll
    for (int i = 0; i < 8; i++)
      #pragma unroll
      for (int d = 0; d < 8; d++) o[i][d] = bo[8 * h + d];
    const float* wo = woT + 8 * h;
    #pragma unroll 2
    for (int c = 0; c < 64; c += 2) {
      float4 w0 = *(const float4*)(wo + c * 64);
      float4 w1 = *(const float4*)(wo + c * 64 + 4);
      float4 w2 = *(const float4*)(wo + (c + 1) * 64);
      float4 w3 = *(const float4*)(wo + (c + 1) * 64 + 4);
      #pragma unroll
      for (int i = 0; i < 8; i++) {
        float2 a2 = *(const float2*)(ao + (l + 32 * i) * PAD + c);
        o[i][0] = fmaf(a2.x, w0.x, o[i][0]);
        o[i][1] = fmaf(a2.x, w0.y, o[i][1]);
        o[i][2] = fmaf(a2.x, w0.z, o[i][2]);
        o[i][3] = fmaf(a2.x, w0.w, o[i][3]);
        o[i][4] = fmaf(a2.x, w1.x, o[i][4]);
        o[i][5] = fmaf(a2.x, w1.y, o[i][5]);
        o[i][6] = fmaf(a2.x, w1.z, o[i][6]);
        o[i][7] = fmaf(a2.x, w1.w, o[i][7]);
        o[i][0] = fmaf(a2.y, w2.x, o[i][0]);
        o[i][1] = fmaf(a2.y, w2.y, o[i][1]);
        o[i][2] = fmaf(a2.y, w2.z, o[i][2]);
        o[i][3] = fmaf(a2.y, w2.w, o[i][3]);
        o[i][4] = fmaf(a2.y, w3.x, o[i][4]);
        o[i][5] = fmaf(a2.y, w3.y, o[i][5]);
        o[i][6] = fmaf(a2.y, w3.z, o[i][6]);
        o[i][7] = fmaf(a2.y, w3.w, o[i][7]);
      }
    }
    float* ob = out + b * (CHN * HW) + p0 + l;
    #pragma unroll
    for (int i = 0; i < 8; i++)
      #pragma unroll
      for (int d = 0; d < 8; d++) ob[(8 * h + d) * HW + 32 * i] = o[i][d];
  }
}

extern "C" void kernel_launch(void* const* d_in, const int* in_sizes, int n_in,
                              void* d_out, int out_size, void* d_ws, size_t ws_size,
                              hipStream_t stream) {
  const float* z    = (const float*)d_in[0];
  const float* cond = (const float*)d_in[1];
  const float* Wq = (const float*)d_in[2];  const float* bq = (const float*)d_in[3];
  const float* Aq = (const float*)d_in[4];  const float* Bq = (const float*)d_in[5];
  const float* Wk = (const float*)d_in[6];  const float* bk = (const float*)d_in[7];
  const float* Ak = (const float*)d_in[8];  const float* Bk = (const float*)d_in[9];
  const float* Wv = (const float*)d_in[10]; const float* bv = (const float*)d_in[11];
  const float* Av = (const float*)d_in[12]; const float* Bv = (const float*)d_in[13];
  const float* Wo = (const float*)d_in[14]; const float* bo = (const float*)d_in[15];
  const float* Ao = (const float*)d_in[16]; const float* Bo = (const float*)d_in[17];
  float* ws  = (float*)d_ws;
  float* out = (float*)d_out;

  prep_weights<<<416, 256, 0, stream>>>(Wq, Aq, Bq, Wk, Ak, Bk, Wv, Av, Bv, Wo, Ao, Bo, ws);
  kvproj<<<dim3(12, 2, 16), 128, 0, stream>>>(cond, ws + OFF_WK, ws + OFF_WV, ws + OFF_PA);
  kvreduce<<<616, 256, 0, stream>>>(ws + OFF_PA, bk, bv, ws + OFF_K, ws + OFF_V);
  megattn<<<dim3(16, 16), 256, 0, stream>>>(z, ws + OFF_WQ, bq, ws + OFF_K, ws + OFF_V,
                                            ws + OFF_WO, bo, out);
}